// Round 2
// baseline (377.505 us; speedup 1.0000x reference)
//
#include <hip/hip_runtime.h>

// out[b,o] = radius * (1/sqrt(K)) * sum_k cos(c*(w[o,k]-x[b,k])),  c = 2*pi/8
//          = radius * (1/sqrt(K)) * sum_k [cos(cx)cos(cw) + sin(cx)sin(cw)]
// B=2048, K=32768, O=10.  Memory-bound on reading x (256 MB); round-2 goal is
// latency hiding: software-pipelined x prefetch + SGPR-base/voffset addressing.

#define K_DIM 32768
#define B_DIM 2048
#define O_DIM 10
#define BROWS 4                 // x rows per block
#define KCH 2                   // K chunks (grid = 512 row-groups x 2 = 1024 blocks)
#define KC_LEN (K_DIM / KCH)    // 16384
#define THREADS 256
#define QUADS (KC_LEN / (THREADS * 4))   // 16 iterations per thread
#define KQ (K_DIM / 4)          // row stride in float4 units
#define INV_SQRT_K 0.005524271728019903f

// hardware v_sin/v_cos take REVOLUTIONS: sin(2*pi*r). c*x radians -> r = x/8.

__global__ void wtrig_kernel(const float* __restrict__ w,
                             float* __restrict__ cw,
                             float* __restrict__ sw) {
    int i = blockIdx.x * blockDim.x + threadIdx.x;   // exact: 1280*256 = 327680
    float r = w[i] * 0.125f;
    cw[i] = __builtin_amdgcn_cosf(r);
    sw[i] = __builtin_amdgcn_sinf(r);
}

__global__ __launch_bounds__(THREADS, 4) void gsim_main(
        const float* __restrict__ x,
        const float* __restrict__ cw,
        const float* __restrict__ sw,
        float* __restrict__ part) {
    const int bid = blockIdx.x;
    const int rg = bid >> 1;          // row group
    const int kc = bid & 1;           // k chunk
    const int r0 = rg * BROWS;
    const int t = threadIdx.x;

    float acc[BROWS][O_DIM];
    #pragma unroll
    for (int r = 0; r < BROWS; ++r)
        #pragma unroll
        for (int o = 0; o < O_DIM; ++o) acc[r][o] = 0.f;

    const float4* xq = (const float4*)x;
    const float4* cq = (const float4*)cw;
    const float4* sq = (const float4*)sw;

    // quad index of this thread at iteration 0 within a K row
    const int q0 = kc * (KC_LEN / 4) + t;
    const int xbase = r0 * KQ + q0;       // row r adds r*KQ; iter i adds i*THREADS

    // pipeline prologue: load iteration 0's x quads
    float4 xb[BROWS];
    #pragma unroll
    for (int r = 0; r < BROWS; ++r) xb[r] = xq[xbase + r * KQ];

    #pragma unroll 2
    for (int i = 0; i < QUADS; ++i) {
        // consume xb -> trig (waitcnt for the prefetch lands here)
        float cs[BROWS][4], sn[BROWS][4];
        #pragma unroll
        for (int r = 0; r < BROWS; ++r) {
            const float* xp = (const float*)&xb[r];
            #pragma unroll
            for (int j = 0; j < 4; ++j) {
                float rr = xp[j] * 0.125f;      // revolutions
                cs[r][j] = __builtin_amdgcn_cosf(rr);
                sn[r][j] = __builtin_amdgcn_sinf(rr);
            }
        }

        // issue next iteration's x loads now; they stay in flight across the
        // entire o-loop below (~640 VALU cycles per wave)
        if (i + 1 < QUADS) {
            const int nb = xbase + (i + 1) * THREADS;
            #pragma unroll
            for (int r = 0; r < BROWS; ++r) xb[r] = xq[nb + r * KQ];
        }

        const int wq = q0 + i * THREADS;
        #pragma unroll
        for (int o = 0; o < O_DIM; ++o) {
            float4 cv = cq[o * KQ + wq];
            float4 sv = sq[o * KQ + wq];
            const float* cp = (const float*)&cv;
            const float* sp = (const float*)&sv;
            #pragma unroll
            for (int r = 0; r < BROWS; ++r)
                #pragma unroll
                for (int j = 0; j < 4; ++j)
                    acc[r][o] += cs[r][j] * cp[j] + sn[r][j] * sp[j];
        }
    }

    // 64-lane butterfly reduction per accumulator
    #pragma unroll
    for (int r = 0; r < BROWS; ++r)
        #pragma unroll
        for (int o = 0; o < O_DIM; ++o) {
            float v = acc[r][o];
            #pragma unroll
            for (int off = 32; off > 0; off >>= 1)
                v += __shfl_xor(v, off, 64);
            acc[r][o] = v;
        }

    __shared__ float red[THREADS / 64][BROWS * O_DIM];
    const int wave = t >> 6;
    const int lane = t & 63;
    if (lane == 0) {
        #pragma unroll
        for (int r = 0; r < BROWS; ++r)
            #pragma unroll
            for (int o = 0; o < O_DIM; ++o)
                red[wave][r * O_DIM + o] = acc[r][o];
    }
    __syncthreads();
    if (t < BROWS * O_DIM) {
        float v = red[0][t] + red[1][t] + red[2][t] + red[3][t];
        part[(size_t)kc * (B_DIM * O_DIM)
             + (size_t)(r0 + t / O_DIM) * O_DIM + (t % O_DIM)] = v;
    }
}

__global__ void finalize_kernel(const float* __restrict__ part,
                                const float* __restrict__ radius,
                                float* __restrict__ out) {
    int i = blockIdx.x * blockDim.x + threadIdx.x;
    if (i < B_DIM * O_DIM) {
        float v = part[i] + part[(size_t)B_DIM * O_DIM + i];
        out[i] = v * radius[0] * INV_SQRT_K;
    }
}

extern "C" void kernel_launch(void* const* d_in, const int* in_sizes, int n_in,
                              void* d_out, int out_size, void* d_ws, size_t ws_size,
                              hipStream_t stream) {
    const float* x      = (const float*)d_in[0];
    const float* w      = (const float*)d_in[1];
    const float* radius = (const float*)d_in[2];
    float* out = (float*)d_out;

    // workspace layout: cw[10][32768] f32 | sw[10][32768] f32 | part[2][2048][10] f32
    float* cw   = (float*)d_ws;
    float* sw   = cw + (size_t)O_DIM * K_DIM;
    float* part = sw + (size_t)O_DIM * K_DIM;

    hipLaunchKernelGGL(wtrig_kernel, dim3((O_DIM * K_DIM) / THREADS), dim3(THREADS),
                       0, stream, w, cw, sw);
    hipLaunchKernelGGL(gsim_main, dim3((B_DIM / BROWS) * KCH), dim3(THREADS),
                       0, stream, x, cw, sw, part);
    hipLaunchKernelGGL(finalize_kernel, dim3((B_DIM * O_DIM + THREADS - 1) / THREADS),
                       dim3(THREADS), 0, stream, part, radius, out);
}

// Round 4
// 73.561 us; speedup vs baseline: 5.1318x; 5.1318x over previous
//
#include <hip/hip_runtime.h>

// out[b,o] = radius * (1/sqrt(K)) * sum_k cos(c*(w[o,k]-x[b,k])),  c = 2*pi/8
//          = radius * (1/sqrt(K)) * sum_k [cos(cx)cos(cw) + sin(cx)sin(cw)]
// B=2048, K=32768, O=10.
// Round 4: w-trig packed as (cos,sin) f16 pairs -> 10 loads/iter instead of 20,
// inner op = v_dot2_f32_f16 (one instr per (r,o,k)). Plain launch_bounds(256)
// (round-2's (256,4) forced VGPR=64 -> 742 MB scratch spill).
// Fix vs round 3: bit_cast cvt_pkrtz's __fp16 vector to _Float16 vector.

typedef _Float16 half2_t __attribute__((ext_vector_type(2)));

#define K_DIM 32768
#define B_DIM 2048
#define O_DIM 10
#define BROWS 4                 // x rows per block
#define KCH 2                   // K chunks (grid = 512 row-groups x 2 = 1024 blocks)
#define KC_LEN (K_DIM / KCH)    // 16384
#define THREADS 256
#define QUADS (KC_LEN / (THREADS * 4))   // 16 iterations per thread
#define KQ (K_DIM / 4)          // row stride in float4 / half2x4 units
#define INV_SQRT_K 0.005524271728019903f

// hardware v_sin/v_cos take REVOLUTIONS: sin(2*pi*r). c*x radians -> r = x/8.

__device__ __forceinline__ half2_t pack_cs(float c, float s) {
    return __builtin_bit_cast(half2_t, __builtin_amdgcn_cvt_pkrtz(c, s));
}

__device__ __forceinline__ float dot2(half2_t a, half2_t b, float acc) {
#if __has_builtin(__builtin_amdgcn_fdot2)
    return __builtin_amdgcn_fdot2(a, b, acc, false);
#else
    return acc + (float)a.x * (float)b.x + (float)a.y * (float)b.y;
#endif
}

__global__ void wtrig_kernel(const float* __restrict__ w,
                             half2_t* __restrict__ wp) {
    int i = blockIdx.x * blockDim.x + threadIdx.x;   // exact: 1280*256 = 327680
    float r = w[i] * 0.125f;
    wp[i] = pack_cs(__builtin_amdgcn_cosf(r), __builtin_amdgcn_sinf(r));
}

__global__ __launch_bounds__(THREADS) void gsim_main(
        const float* __restrict__ x,
        const half2_t* __restrict__ wp,
        float* __restrict__ part) {
    const int bid = blockIdx.x;
    const int rg = bid >> 1;          // row group
    const int kc = bid & 1;           // k chunk
    const int r0 = rg * BROWS;
    const int t = threadIdx.x;

    float acc[BROWS][O_DIM];
    #pragma unroll
    for (int r = 0; r < BROWS; ++r)
        #pragma unroll
        for (int o = 0; o < O_DIM; ++o) acc[r][o] = 0.f;

    const float4* xq = (const float4*)x;
    const float4* wq = (const float4*)wp;   // one float4 = 4 half2 = 4 k of (c,s)

    const int q0 = kc * (KC_LEN / 4) + t;   // quad index at iteration 0
    const int xbase = r0 * KQ + q0;

    // pipeline prologue: iteration 0's x quads
    float4 xb[BROWS];
    #pragma unroll
    for (int r = 0; r < BROWS; ++r) xb[r] = xq[xbase + r * KQ];

    #pragma unroll 2
    for (int i = 0; i < QUADS; ++i) {
        const int wqi = q0 + i * THREADS;

        // issue all w loads first; their latency hides under the trig below
        float4 wv[O_DIM];
        #pragma unroll
        for (int o = 0; o < O_DIM; ++o) wv[o] = wq[o * KQ + wqi];

        // trig + f16 pack (x-prefetch waitcnt lands here)
        half2_t pk[BROWS][4];
        #pragma unroll
        for (int r = 0; r < BROWS; ++r) {
            const float* xp = (const float*)&xb[r];
            #pragma unroll
            for (int j = 0; j < 4; ++j) {
                float rr = xp[j] * 0.125f;      // revolutions
                pk[r][j] = pack_cs(__builtin_amdgcn_cosf(rr),
                                   __builtin_amdgcn_sinf(rr));
            }
        }

        // issue next iteration's x loads; in flight across the dot2 loop
        if (i + 1 < QUADS) {
            const int nb = xbase + (i + 1) * THREADS;
            #pragma unroll
            for (int r = 0; r < BROWS; ++r) xb[r] = xq[nb + r * KQ];
        }

        // accumulate: one v_dot2_f32_f16 per (r,o,k-pair-of-2), 4 per float4
        #pragma unroll
        for (int o = 0; o < O_DIM; ++o) {
            const half2_t* wh = (const half2_t*)&wv[o];
            #pragma unroll
            for (int r = 0; r < BROWS; ++r)
                #pragma unroll
                for (int j = 0; j < 4; ++j)
                    acc[r][o] = dot2(pk[r][j], wh[j], acc[r][o]);
        }
    }

    // 64-lane butterfly reduction per accumulator
    #pragma unroll
    for (int r = 0; r < BROWS; ++r)
        #pragma unroll
        for (int o = 0; o < O_DIM; ++o) {
            float v = acc[r][o];
            #pragma unroll
            for (int off = 32; off > 0; off >>= 1)
                v += __shfl_xor(v, off, 64);
            acc[r][o] = v;
        }

    __shared__ float red[THREADS / 64][BROWS * O_DIM];
    const int wave = t >> 6;
    const int lane = t & 63;
    if (lane == 0) {
        #pragma unroll
        for (int r = 0; r < BROWS; ++r)
            #pragma unroll
            for (int o = 0; o < O_DIM; ++o)
                red[wave][r * O_DIM + o] = acc[r][o];
    }
    __syncthreads();
    if (t < BROWS * O_DIM) {
        float v = red[0][t] + red[1][t] + red[2][t] + red[3][t];
        part[(size_t)kc * (B_DIM * O_DIM)
             + (size_t)(r0 + t / O_DIM) * O_DIM + (t % O_DIM)] = v;
    }
}

__global__ void finalize_kernel(const float* __restrict__ part,
                                const float* __restrict__ radius,
                                float* __restrict__ out) {
    int i = blockIdx.x * blockDim.x + threadIdx.x;
    if (i < B_DIM * O_DIM) {
        float v = part[i] + part[(size_t)B_DIM * O_DIM + i];
        out[i] = v * radius[0] * INV_SQRT_K;
    }
}

extern "C" void kernel_launch(void* const* d_in, const int* in_sizes, int n_in,
                              void* d_out, int out_size, void* d_ws, size_t ws_size,
                              hipStream_t stream) {
    const float* x      = (const float*)d_in[0];
    const float* w      = (const float*)d_in[1];
    const float* radius = (const float*)d_in[2];
    float* out = (float*)d_out;

    // workspace: wp[10][32768] half2 (1.31 MB) | part[2][2048][10] f32
    half2_t* wpd = (half2_t*)d_ws;
    float* part  = (float*)(wpd + (size_t)O_DIM * K_DIM);

    hipLaunchKernelGGL(wtrig_kernel, dim3((O_DIM * K_DIM) / THREADS), dim3(THREADS),
                       0, stream, w, wpd);
    hipLaunchKernelGGL(gsim_main, dim3((B_DIM / BROWS) * KCH), dim3(THREADS),
                       0, stream, x, wpd, part);
    hipLaunchKernelGGL(finalize_kernel, dim3((B_DIM * O_DIM + THREADS - 1) / THREADS),
                       dim3(THREADS), 0, stream, part, radius, out);
}